// Round 9
// baseline (176.978 us; speedup 1.0000x reference)
//
#include <hip/hip_runtime.h>

// BatchNeuralKB: out[b] = max_f exp(-clamp(||q_b - f||^2,0)/2)
//             = exp(-0.5 * clamp(qsq[b] + min_f(fsq[f] - 2*dot(q_b,f)), 0))
//
// R21 FULL path = R20 with ONE parameter change: gemm occupancy 2 -> 3-4
// blocks/CU (grid 1024 = (F/512, B/256), ntiles=8, launch_bounds(256,3)).
// R8 evidence: R17-vs-R18 gemm choice is noise (157.6 vs 159.7); the only
// untested lever on the slimmed gemm is cross-block overlap of barrier/fold
// tails (all slimmed variants ran exactly 2 blocks/CU; VGPR=128 & LDS=24KB
// permit 4). R13's 1024-block run was confounded by the widen4 remat bug.
//  - prep: R19 (verified): 16 rows/block, 16-lane group/row, no LDS.
//  - gemm: R17 structure (fp4 MX, 64-fact tiles, 2x12KB dbuf, pre-widened A,
//    zero-C first slice, depth-2 3-tuple B pipe, in-shadow folds, setprio,
//    clean atomicMin epilogue).
//  - finalize: separate kernel (fused version falsified in R16).
// Layout identical to R13..R20 (k-permuted + chunk-swizzled, conflicts==0).
// atomicMin on uint bits of clamped d2 (>=0, order-preserving).

typedef __attribute__((ext_vector_type(4))) float f32x4;
typedef __attribute__((ext_vector_type(4))) int i32x4;
typedef __attribute__((ext_vector_type(8))) int i32x8;
typedef __attribute__((ext_vector_type(8))) __bf16 bf16x8;        // lean path
typedef __attribute__((ext_vector_type(4))) unsigned short us4;   // lean path

#define AS1 __attribute__((address_space(1)))
#define AS3 __attribute__((address_space(3)))
__device__ __forceinline__ void gl2lds16(const void* g, void* l) {
    __builtin_amdgcn_global_load_lds((const AS1 unsigned int*)g,
                                     (AS3 unsigned int*)l, 16, 0, 0);
}

// fp32 -> fp4 e2m1 nibble, nearest (RNE at code boundaries), saturate to 6.
// codes: 0,0.5,1,1.5,2,3,4,6 (x sign)
__device__ __forceinline__ unsigned f2e2m1(float x) {
    float a = fminf(fabsf(x), 6.0f);
    // piecewise linear map so that rint() lands on the nearest e2m1 code:
    // [0,2): t=2a (codes 0..4); [2,4): t=a+2 (codes 4..6); [4,6]: t=a/2+4 (6..7)
    float t = (a < 2.0f) ? a * 2.0f : ((a < 4.0f) ? a + 2.0f : a * 0.5f + 4.0f);
    unsigned n = (unsigned)(int)rintf(t);
    return n | ((__float_as_uint(x) >> 28) & 8u);
}

// pack 8 floats into 8 e2m1 nibbles (one 4B word)
__device__ __forceinline__ unsigned pack8(const float4 v0, const float4 v1) {
    return f2e2m1(v0.x)         | (f2e2m1(v0.y) << 4)  |
           (f2e2m1(v0.z) << 8)  | (f2e2m1(v0.w) << 12) |
           (f2e2m1(v1.x) << 16) | (f2e2m1(v1.y) << 20) |
           (f2e2m1(v1.z) << 24) | (f2e2m1(v1.w) << 28);
}

__device__ __forceinline__ float sq8(const float4 v0, const float4 v1) {
    return v0.x * v0.x + v0.y * v0.y + v0.z * v0.z + v0.w * v0.w +
           v1.x * v1.x + v1.y * v1.y + v1.z * v1.z + v1.w * v1.w;
}

// round-to-nearest-even fp32 -> bf16 (lean path)
__device__ __forceinline__ unsigned short f2bf(float f) {
    unsigned int u = __float_as_uint(f);
    u = (u + 0x7fffu + ((u >> 16) & 1u)) >> 16;
    return (unsigned short)u;
}

// ---------- R19 prep (verified): 16 rows/block, 16-lane group per row ------
// Row = 192 B = 3 K-slices x 64 B; within a slice, logical 16B chunk c16 is
// stored at position c16 ^ ((row>>1)&3) (same verified swizzle as R13+).
__global__ void prep_kernel(const float* __restrict__ rel, const float* __restrict__ a1,
                            const float* __restrict__ a2, const float* __restrict__ fr,
                            const float* __restrict__ fa1, const float* __restrict__ fa2,
                            unsigned char* __restrict__ Qf, unsigned char* __restrict__ Ff,
                            float* __restrict__ qsq, float* __restrict__ fsq,
                            unsigned int* __restrict__ outbits, int B, int F) {
    const int tid = threadIdx.x;
    const int nqb = B >> 4;
    const bool isQ = (int)blockIdx.x < nqb;
    const int rbase = (isQ ? (int)blockIdx.x : (int)blockIdx.x - nqb) << 4;
    const float* p0 = isQ ? rel : fr;
    const float* p1 = isQ ? a1 : fa1;
    const float* p2 = isQ ? a2 : fa2;
    unsigned char* outb = isQ ? Qf : Ff;
    float* sq = isQ ? qsq : fsq;

    const int r = tid >> 4;            // row within block, 0..15
    const int g = tid & 15;            // 8-float chunk within each part
    const int row = rbase + r;
    const size_t roff = (size_t)row * 128 + g * 8;

    // 3 independent 32B loads (one per part), all issued before converts.
    const float4 a0 = *(const float4*)(p0 + roff);
    const float4 b0 = *(const float4*)(p0 + roff + 4);
    const float4 a1v = *(const float4*)(p1 + roff);
    const float4 b1v = *(const float4*)(p1 + roff + 4);
    const float4 a2v = *(const float4*)(p2 + roff);
    const float4 b2v = *(const float4*)(p2 + roff + 4);

    // swizzled output position (same formula as R13's conv_row_fp4)
    const int cs = (g >> 2) ^ ((row >> 1) & 3);
    unsigned char* orow = outb + (size_t)row * 192 + cs * 16 + (g & 3) * 4;
    *(unsigned*)(orow)       = pack8(a0, b0);
    *(unsigned*)(orow + 64)  = pack8(a1v, b1v);
    *(unsigned*)(orow + 128) = pack8(a2v, b2v);

    // partial sumsq over this thread's 24 elems, 16-lane group reduce
    float s = sq8(a0, b0) + sq8(a1v, b1v) + sq8(a2v, b2v);
    s += __shfl_xor(s, 1, 64);
    s += __shfl_xor(s, 2, 64);
    s += __shfl_xor(s, 4, 64);
    s += __shfl_xor(s, 8, 64);
    if (g == 0) sq[row] = s;

    if (blockIdx.x == 0) {
        for (int i = tid; i < B; i += 256) outbits[i] = 0x7f800000u;
    }
}

// Stage one 64-fact fp4 tile (12 KB, all of K) into buf. LDS layout
// [kk][row][ch16B]: iid*16 = kk*4096 + row*64 + ch*16.
__device__ __forceinline__ void stage_tile4(const unsigned char* __restrict__ Ff,
                                            unsigned char* buf, int n0, int tid) {
#pragma unroll
    for (int it = 0; it < 3; ++it) {
        int iid = it * 256 + tid;  // [0,768)
        gl2lds16(Ff + (size_t)(n0 + ((iid >> 2) & 63)) * 192 +
                     (iid >> 8) * 64 + (iid & 3) * 16,
                 buf + (size_t)iid * 16);
    }
}

// ---------- R21 GEMM: R17 structure at 3-4 blocks/CU ------------------------
__global__ __launch_bounds__(256, 3)
void gemm_pipe_kernel(const unsigned char* __restrict__ Qf,  // [M][192] fp4 permuted
                      const unsigned char* __restrict__ Ff,  // [N][192] fp4 permuted
                      const float* __restrict__ qsq, const float* __restrict__ fsq,
                      unsigned int* __restrict__ outbits, int ntiles) {
    __shared__ __align__(16) unsigned char Bs[2][12288];  // 2 x 12 KB

    const int tid = threadIdx.x;
    const int lane = tid & 63;
    const int wid = tid >> 6;          // wave owns m-rows [wid*64, wid*64+64)
    const int col = lane & 15, quad = lane >> 4;
    const int swc = ((col >> 1) & 3);
    const int cp = (quad ^ swc) * 16;  // swizzled chunk byte offset
    const int m0 = blockIdx.y * 256;
    const int nbase = blockIdx.x * (ntiles * 64);
    const int SCL = 0x7f;  // e8m0 exponent 127 -> scale = 2^0 = 1.0

    // A operand fully resident AND pre-widened: 4 i x 3 kk x 8 regs = 96 VGPRs
    // (high halves zero, written once -> no widen movs inside the loop).
    i32x8 af8[4][3];
#pragma unroll
    for (int i = 0; i < 4; ++i) {
        const unsigned char* base = Qf + (size_t)(m0 + wid * 64 + i * 16 + col) * 192;
#pragma unroll
        for (int kk = 0; kk < 3; ++kk) {
            i32x4 t = *(const i32x4*)(base + kk * 64 + cp);
            af8[i][kk][0] = t[0]; af8[i][kk][1] = t[1];
            af8[i][kk][2] = t[2]; af8[i][kk][3] = t[3];
            af8[i][kk][4] = 0; af8[i][kk][5] = 0;
            af8[i][kk][6] = 0; af8[i][kk][7] = 0;
        }
    }

    // persistent zero C operand (first K-slice MFMA writes acc = A*B + 0)
    const f32x4 zero4 = {0.f, 0.f, 0.f, 0.f};

    float rowmin[16];
#pragma unroll
    for (int v = 0; v < 16; ++v) rowmin[v] = 3.0e38f;

    // fsq seeds prefetched one tile ahead (registers; no global dep at fold)
    float fs_cur[4], fs_nxt[4];
#pragma unroll
    for (int j = 0; j < 4; ++j) fs_cur[j] = fsq[nbase + j * 16 + col];

    // Three rotating B tuples; high halves zeroed ONCE (persist across tiles).
    i32x8 bv[3];
#pragma unroll
    for (int r = 0; r < 3; ++r) {
        bv[r][4] = 0; bv[r][5] = 0; bv[r][6] = 0; bv[r][7] = 0;
    }

    f32x4 acc[4][4];  // NOT seeded: kk==0 MFMA uses zero4 as C

#define LOADB(S, R)                                                            \
        {                                                                      \
            const int _j = (S) / 3, _kk = (S) % 3;                             \
            i32x4 _t = *(const i32x4*)(bb + _kk * 4096 + (_j * 16 + col) * 64 + cp); \
            bv[R][0] = _t[0]; bv[R][1] = _t[1];                                \
            bv[R][2] = _t[2]; bv[R][3] = _t[3];                                \
        }
#define MFMAS(S, R)                                                            \
        {                                                                      \
            const int _j = (S) / 3, _kk = (S) % 3;                             \
            if (_kk == 0) {                                                    \
                _Pragma("unroll") for (int _i = 0; _i < 4; ++_i)               \
                    acc[_i][_j] = __builtin_amdgcn_mfma_scale_f32_16x16x128_f8f6f4( \
                        af8[_i][0], bv[R], zero4, 4, 4, 0, SCL, 0, SCL);       \
            } else {                                                           \
                _Pragma("unroll") for (int _i = 0; _i < 4; ++_i)               \
                    acc[_i][_j] = __builtin_amdgcn_mfma_scale_f32_16x16x128_f8f6f4( \
                        af8[_i][_kk], bv[R], acc[_i][_j], 4, 4, 0, SCL, 0, SCL); \
            }                                                                  \
        }
#define FOLDJ(J)                                                               \
        {                                                                      \
            _Pragma("unroll") for (int _i = 0; _i < 4; ++_i)                   \
                _Pragma("unroll") for (int _r = 0; _r < 4; ++_r)               \
                    rowmin[_i * 4 + _r] = fminf(rowmin[_i * 4 + _r],           \
                        fmaf(-2.0f, acc[_i][(J)][_r], fs_cur[(J)]));           \
        }

    stage_tile4(Ff, Bs[0], nbase, tid);  // prologue prefetch
    for (int t = 0; t < ntiles; ++t) {
        __syncthreads();  // drains tile t's staging (issued one full round ago)
        if (t + 1 < ntiles) {
            stage_tile4(Ff, Bs[(t + 1) & 1], nbase + (t + 1) * 64, tid);
#pragma unroll
            for (int j = 0; j < 4; ++j)
                fs_nxt[j] = fsq[nbase + (t + 1) * 64 + j * 16 + col];
        }
        const unsigned char* bb = Bs[t & 1];

        // 12 steps s=(j,kk); depth-2 B ds_read pipeline (3 rotating tuples);
        // fold j shadowed at step 3j+3 (acc[j] final after step 3j+2, not
        // rewritten until next tile's zero-C MFMA). Only j=3's fold exposed.
        __builtin_amdgcn_s_setprio(1);
        LOADB(0, 0);
        LOADB(1, 1);
#pragma unroll
        for (int s = 0; s < 12; ++s) {
            if (s + 2 < 12) LOADB(s + 2, (s + 2) % 3);
            if (s >= 3 && s % 3 == 0) FOLDJ(s / 3 - 1);   // s=3,6,9 -> j=0,1,2
            MFMAS(s, s % 3);
        }
        __builtin_amdgcn_s_setprio(0);
        FOLDJ(3);

#pragma unroll
        for (int j = 0; j < 4; ++j) fs_cur[j] = fs_nxt[j];
    }
#undef LOADB
#undef MFMAS
#undef FOLDJ

    // per-wave epilogue (each wave owns exclusive m-rows): min over 16 cols,
    // then one atomic per row.
#pragma unroll
    for (int v = 0; v < 16; ++v) {
        float mn = rowmin[v];
#pragma unroll
        for (int off = 1; off < 16; off <<= 1) mn = fminf(mn, __shfl_xor(mn, off, 64));
        rowmin[v] = mn;
    }
    if (col == 0) {
#pragma unroll
        for (int i = 0; i < 4; ++i)
#pragma unroll
            for (int r = 0; r < 4; ++r) {
                const int row = m0 + wid * 64 + i * 16 + quad * 4 + r;
                float d2 = fmaxf(qsq[row] + rowmin[i * 4 + r], 0.0f);
                atomicMin(outbits + row, __float_as_uint(d2));
            }
    }
}

__global__ void finalize_kernel(float* out, int n) {
    int i = blockIdx.x * blockDim.x + threadIdx.x;
    if (i < n) {
        float d2 = __uint_as_float(((unsigned int*)out)[i]);
        out[i] = expf(-0.5f * d2);
    }
}

// ---------- fallbacks (verified in earlier rounds) ----------
__global__ void init_min_kernel(unsigned int* ob, int n) {
    int i = blockIdx.x * blockDim.x + threadIdx.x;
    if (i < n) ob[i] = 0x7f800000u;
}

__global__ void conv_rows_kernel(const float* __restrict__ p0, const float* __restrict__ p1,
                                 const float* __restrict__ p2, unsigned short* __restrict__ outb,
                                 float* __restrict__ sq, int nrows) {
    const int lane = threadIdx.x & 63;
    const int wave = threadIdx.x >> 6;
    const int row = blockIdx.x * 4 + wave;
    if (row >= nrows) return;
    float s = 0.f;
#pragma unroll
    for (int c = 0; c < 6; ++c) {
        int k = c * 64 + lane;
        const float* src = (k < 128) ? p0 : (k < 256) ? p1 : p2;
        float v = src[(size_t)row * 128 + (k & 127)];
        s += v * v;
        if (outb) outb[(size_t)row * 384 + k] = f2bf(v);
    }
#pragma unroll
    for (int off = 32; off >= 1; off >>= 1) s += __shfl_xor(s, off, 64);
    if (lane == 0) sq[row] = s;
}

__global__ __launch_bounds__(256)
void gemm_lean_kernel(const unsigned short* __restrict__ Qb,
                      const float* __restrict__ f0, const float* __restrict__ f1,
                      const float* __restrict__ f2,
                      const float* __restrict__ qsq, const float* __restrict__ fsq,
                      unsigned int* __restrict__ outbits, int K) {
    __shared__ __align__(16) unsigned short As[128 * 32];
    __shared__ __align__(16) unsigned short Bs[128 * 32];
    __shared__ float smin[128 * 2];

    const int tid = threadIdx.x;
    const int lane = tid & 63;
    const int wid = tid >> 6;
    const int wm = wid >> 1, wn = wid & 1;
    const int col = lane & 15, quad = lane >> 4;
    const int m0 = blockIdx.x * 128;
    const int n0 = blockIdx.y * 128;

    f32x4 acc[4][4];
#pragma unroll
    for (int i = 0; i < 4; ++i)
#pragma unroll
        for (int j = 0; j < 4; ++j) {
            f32x4 z = {0.f, 0.f, 0.f, 0.f};
            acc[i][j] = z;
        }

    const int nk = K >> 5;
    for (int kk = 0; kk < nk; ++kk) {
        const int k0 = kk << 5;
        __syncthreads();
#pragma unroll
        for (int it = 0; it < 2; ++it) {
            int iid = it * 256 + tid;
            int row = iid >> 2, ch = iid & 3;
            gl2lds16(Qb + ((size_t)(m0 + row) * K + k0 + ch * 8), As + (row * 32 + ch * 8));
        }
        const float* src = (k0 < 128) ? f0 : (k0 < 256) ? f1 : f2;
        const int kp = k0 & 127;
#pragma unroll
        for (int it = 0; it < 4; ++it) {
            int iid = it * 256 + tid;
            int row = iid >> 3, ch = iid & 7;
            const float4 v = *(const float4*)(src + (size_t)(n0 + row) * 128 + kp + ch * 4);
            us4 w = {f2bf(v.x), f2bf(v.y), f2bf(v.z), f2bf(v.w)};
            *(us4*)(Bs + (row * 32 + ch * 4)) = w;
        }
        __syncthreads();

        bf16x8 afr[4], bfv[4];
#pragma unroll
        for (int i = 0; i < 4; ++i)
            afr[i] = *(const bf16x8*)(As + ((wm * 64 + i * 16 + col) * 32 + quad * 8));
#pragma unroll
        for (int j = 0; j < 4; ++j)
            bfv[j] = *(const bf16x8*)(Bs + ((wn * 64 + j * 16 + col) * 32 + quad * 8));
#pragma unroll
        for (int i = 0; i < 4; ++i)
#pragma unroll
            for (int j = 0; j < 4; ++j)
                acc[i][j] = __builtin_amdgcn_mfma_f32_16x16x32_bf16(afr[i], bfv[j], acc[i][j], 0, 0, 0);
    }

    float fs[4];
#pragma unroll
    for (int j = 0; j < 4; ++j) fs[j] = fsq[n0 + wn * 64 + j * 16 + col];
#pragma unroll
    for (int i = 0; i < 4; ++i) {
#pragma unroll
        for (int r = 0; r < 4; ++r) {
            const int mrow = wm * 64 + i * 16 + quad * 4 + r;
            const float qs = qsq[m0 + mrow];
            float mn = 3.0e38f;
#pragma unroll
            for (int j = 0; j < 4; ++j) {
                float d2 = qs + fs[j] - 2.0f * acc[i][j][r];
                mn = fminf(mn, fmaxf(d2, 0.0f));
            }
#pragma unroll
            for (int off = 1; off < 16; off <<= 1) mn = fminf(mn, __shfl_xor(mn, off, 64));
            if (col == 0) smin[mrow * 2 + wn] = mn;
        }
    }
    __syncthreads();
    if (tid < 128) {
        float v = fminf(smin[tid * 2 + 0], smin[tid * 2 + 1]);
        atomicMin(outbits + m0 + tid, __float_as_uint(v));
    }
}

__global__ __launch_bounds__(256)
void tier3_kernel(const float* __restrict__ rel, const float* __restrict__ a1,
                  const float* __restrict__ a2, const float* __restrict__ fr,
                  const float* __restrict__ fa1, const float* __restrict__ fa2,
                  unsigned int* __restrict__ outbits) {
    __shared__ float qs[16][384];
    __shared__ float red[4][16];
    const int tid = threadIdx.x;
    const int qbase = blockIdx.y * 16;
    const int fbase = blockIdx.x * 2048;
    for (int i = tid; i < 16 * 384; i += 256) {
        int r = i / 384, c = i % 384;
        const float* src = (c < 128) ? rel : (c < 256) ? a1 : a2;
        qs[r][c] = src[(size_t)(qbase + r) * 128 + (c & 127)];
    }
    __syncthreads();
    float mn[16];
#pragma unroll
    for (int q = 0; q < 16; ++q) mn[q] = 3.0e38f;
    for (int fi = 0; fi < 2048; fi += 256) {
        const int f = fbase + fi + tid;
        float acc[16];
#pragma unroll
        for (int q = 0; q < 16; ++q) acc[q] = 0.f;
#pragma unroll
        for (int p = 0; p < 3; ++p) {
            const float* fptr = ((p == 0) ? fr : (p == 1) ? fa1 : fa2) + (size_t)f * 128;
            for (int k4 = 0; k4 < 32; ++k4) {
                const float4 fv = *(const float4*)(fptr + k4 * 4);
#pragma unroll
                for (int q = 0; q < 16; ++q) {
                    float d0 = fv.x - qs[q][p * 128 + k4 * 4 + 0];
                    float d1 = fv.y - qs[q][p * 128 + k4 * 4 + 1];
                    float d2 = fv.z - qs[q][p * 128 + k4 * 4 + 2];
                    float d3 = fv.w - qs[q][p * 128 + k4 * 4 + 3];
                    acc[q] += d0 * d0 + d1 * d1 + d2 * d2 + d3 * d3;
                }
            }
        }
#pragma unroll
        for (int q = 0; q < 16; ++q) mn[q] = fminf(mn[q], fmaxf(acc[q], 0.f));
    }
#pragma unroll
    for (int q = 0; q < 16; ++q) {
        float v = mn[q];
#pragma unroll
        for (int off = 32; off >= 1; off >>= 1) v = fminf(v, __shfl_xor(v, off, 64));
        if ((tid & 63) == 0) red[tid >> 6][q] = v;
    }
    __syncthreads();
    if (tid < 16) {
        float v = fminf(fminf(red[0][tid], red[1][tid]), fminf(red[2][tid], red[3][tid]));
        atomicMin(outbits + qbase + tid, __float_as_uint(v));
    }
}

extern "C" void kernel_launch(void* const* d_in, const int* in_sizes, int n_in,
                              void* d_out, int out_size, void* d_ws, size_t ws_size,
                              hipStream_t stream) {
    const float* rel = (const float*)d_in[0];
    const float* a1 = (const float*)d_in[1];
    const float* a2 = (const float*)d_in[2];
    const float* fr = (const float*)d_in[3];
    const float* fa1 = (const float*)d_in[4];
    const float* fa2 = (const float*)d_in[5];

    const int E = 128, K = 384;
    const int B = in_sizes[0] / E;   // 2048
    const int F = in_sizes[3] / E;   // 65536

    float* out = (float*)d_out;
    unsigned int* outbits = (unsigned int*)d_out;

    const size_t ff_bytes = (size_t)F * 192;     // 12 MB facts fp4
    const size_t qf_bytes = (size_t)B * 192;     // 384 KB queries fp4
    const size_t need_full = ff_bytes + qf_bytes + (size_t)F * 4 + (size_t)B * 4;
    const size_t qb_bytes = (size_t)B * K * 2;
    const size_t need_lean = qb_bytes + (size_t)F * 4 + (size_t)B * 4;

    const bool shapes_ok = (B % 256 == 0) && (F % 1024 == 0);
    if (ws_size >= need_full && shapes_ok) {
        unsigned char* Ff = (unsigned char*)d_ws;
        unsigned char* Qf = (unsigned char*)d_ws + ff_bytes;
        float* fsq = (float*)((char*)d_ws + ff_bytes + qf_bytes);
        float* qsq = fsq + F;
        prep_kernel<<<B / 16 + F / 16, 256, 0, stream>>>(rel, a1, a2, fr, fa1, fa2,
                                                         Qf, Ff, qsq, fsq, outbits, B, F);
        // grid: x = n-groups of 512 facts (8 tiles of 64, double-buffered),
        // y = m-tiles of 256. 1024 blocks -> 3-4 blocks/CU co-resident.
        gemm_pipe_kernel<<<dim3(F / 512, B / 256), 256, 0, stream>>>(
            Qf, Ff, qsq, fsq, outbits, 8);
    } else if (ws_size >= need_lean && B % 128 == 0 && F % 128 == 0) {
        unsigned short* Qb = (unsigned short*)d_ws;
        float* fsq = (float*)((char*)d_ws + qb_bytes);
        float* qsq = fsq + F;
        init_min_kernel<<<(B + 255) / 256, 256, 0, stream>>>(outbits, B);
        conv_rows_kernel<<<B / 4, 256, 0, stream>>>(rel, a1, a2, Qb, qsq, B);
        conv_rows_kernel<<<F / 4, 256, 0, stream>>>(fr, fa1, fa2, nullptr, fsq, F);
        gemm_lean_kernel<<<dim3(B / 128, F / 128), 256, 0, stream>>>(
            Qb, fr, fa1, fa2, qsq, fsq, outbits, K);
    } else {
        init_min_kernel<<<(B + 255) / 256, 256, 0, stream>>>(outbits, B);
        tier3_kernel<<<dim3(F / 2048, B / 16), 256, 0, stream>>>(rel, a1, a2, fr, fa1, fa2, outbits);
    }

    finalize_kernel<<<(B + 255) / 256, 256, 0, stream>>>(out, B);
}

// Round 10
// 156.662 us; speedup vs baseline: 1.1297x; 1.1297x over previous
//
#include <hip/hip_runtime.h>

// BatchNeuralKB: out[b] = max_f exp(-clamp(||q_b - f||^2,0)/2)
//             = exp(-0.5 * clamp(qsq[b] + min_f(fsq[f] - 2*dot(q_b,f)), 0))
//
// R22 = exact revert to the best measured configuration (R7, 157.6 us):
//  - prep: R19 (16 rows/block, 16-lane group per row, no LDS, register sumsq).
//  - gemm: R18 structure, launch_bounds(256,2) -- R9 PROVED (VGPR 128->80,
//    gemm 51us) that this kernel needs ~128 resident VGPRs; 2 blocks/CU is a
//    hard constraint. fp4 MX, 128-fact tiles x8, 2x24KB LDS dbuf, pre-widened
//    A, zero-C per half, kk-outer/j-inner, depth-2 B ds_read pipeline,
//    in-shadow folds, setprio, clean atomicMin epilogue.
//  - finalize: separate kernel (fused version falsified in R16).
// Falsified levers (do not retry): fp8->fp4 rate swap alone (overhead-bound),
// barrier-free global streaming (R14, +13us), fused-finalize atomics (R16,
// +66us), occupancy>2 (R9/R13, VGPR cap kills operand residency), 64 vs 128
// tile (noise). Layout k-permuted + chunk-swizzled, conflicts==0.
// atomicMin on uint bits of clamped d2 (>=0, order-preserving).

typedef __attribute__((ext_vector_type(4))) float f32x4;
typedef __attribute__((ext_vector_type(4))) int i32x4;
typedef __attribute__((ext_vector_type(8))) int i32x8;
typedef __attribute__((ext_vector_type(8))) __bf16 bf16x8;        // lean path
typedef __attribute__((ext_vector_type(4))) unsigned short us4;   // lean path

#define AS1 __attribute__((address_space(1)))
#define AS3 __attribute__((address_space(3)))
__device__ __forceinline__ void gl2lds16(const void* g, void* l) {
    __builtin_amdgcn_global_load_lds((const AS1 unsigned int*)g,
                                     (AS3 unsigned int*)l, 16, 0, 0);
}

// fp32 -> fp4 e2m1 nibble, nearest (RNE at code boundaries), saturate to 6.
// codes: 0,0.5,1,1.5,2,3,4,6 (x sign)
__device__ __forceinline__ unsigned f2e2m1(float x) {
    float a = fminf(fabsf(x), 6.0f);
    // piecewise linear map so that rint() lands on the nearest e2m1 code:
    // [0,2): t=2a (codes 0..4); [2,4): t=a+2 (codes 4..6); [4,6]: t=a/2+4 (6..7)
    float t = (a < 2.0f) ? a * 2.0f : ((a < 4.0f) ? a + 2.0f : a * 0.5f + 4.0f);
    unsigned n = (unsigned)(int)rintf(t);
    return n | ((__float_as_uint(x) >> 28) & 8u);
}

// pack 8 floats into 8 e2m1 nibbles (one 4B word)
__device__ __forceinline__ unsigned pack8(const float4 v0, const float4 v1) {
    return f2e2m1(v0.x)         | (f2e2m1(v0.y) << 4)  |
           (f2e2m1(v0.z) << 8)  | (f2e2m1(v0.w) << 12) |
           (f2e2m1(v1.x) << 16) | (f2e2m1(v1.y) << 20) |
           (f2e2m1(v1.z) << 24) | (f2e2m1(v1.w) << 28);
}

__device__ __forceinline__ float sq8(const float4 v0, const float4 v1) {
    return v0.x * v0.x + v0.y * v0.y + v0.z * v0.z + v0.w * v0.w +
           v1.x * v1.x + v1.y * v1.y + v1.z * v1.z + v1.w * v1.w;
}

// round-to-nearest-even fp32 -> bf16 (lean path)
__device__ __forceinline__ unsigned short f2bf(float f) {
    unsigned int u = __float_as_uint(f);
    u = (u + 0x7fffu + ((u >> 16) & 1u)) >> 16;
    return (unsigned short)u;
}

// ---------- R19 prep (verified): 16 rows/block, 16-lane group per row ------
// Row = 192 B = 3 K-slices x 64 B; within a slice, logical 16B chunk c16 is
// stored at position c16 ^ ((row>>1)&3) (same verified swizzle as R13+).
__global__ void prep_kernel(const float* __restrict__ rel, const float* __restrict__ a1,
                            const float* __restrict__ a2, const float* __restrict__ fr,
                            const float* __restrict__ fa1, const float* __restrict__ fa2,
                            unsigned char* __restrict__ Qf, unsigned char* __restrict__ Ff,
                            float* __restrict__ qsq, float* __restrict__ fsq,
                            unsigned int* __restrict__ outbits, int B, int F) {
    const int tid = threadIdx.x;
    const int nqb = B >> 4;
    const bool isQ = (int)blockIdx.x < nqb;
    const int rbase = (isQ ? (int)blockIdx.x : (int)blockIdx.x - nqb) << 4;
    const float* p0 = isQ ? rel : fr;
    const float* p1 = isQ ? a1 : fa1;
    const float* p2 = isQ ? a2 : fa2;
    unsigned char* outb = isQ ? Qf : Ff;
    float* sq = isQ ? qsq : fsq;

    const int r = tid >> 4;            // row within block, 0..15
    const int g = tid & 15;            // 8-float chunk within each part
    const int row = rbase + r;
    const size_t roff = (size_t)row * 128 + g * 8;

    // 3 independent 32B loads (one per part), all issued before converts.
    const float4 a0 = *(const float4*)(p0 + roff);
    const float4 b0 = *(const float4*)(p0 + roff + 4);
    const float4 a1v = *(const float4*)(p1 + roff);
    const float4 b1v = *(const float4*)(p1 + roff + 4);
    const float4 a2v = *(const float4*)(p2 + roff);
    const float4 b2v = *(const float4*)(p2 + roff + 4);

    // swizzled output position (same formula as R13's conv_row_fp4)
    const int cs = (g >> 2) ^ ((row >> 1) & 3);
    unsigned char* orow = outb + (size_t)row * 192 + cs * 16 + (g & 3) * 4;
    *(unsigned*)(orow)       = pack8(a0, b0);
    *(unsigned*)(orow + 64)  = pack8(a1v, b1v);
    *(unsigned*)(orow + 128) = pack8(a2v, b2v);

    // partial sumsq over this thread's 24 elems, 16-lane group reduce
    float s = sq8(a0, b0) + sq8(a1v, b1v) + sq8(a2v, b2v);
    s += __shfl_xor(s, 1, 64);
    s += __shfl_xor(s, 2, 64);
    s += __shfl_xor(s, 4, 64);
    s += __shfl_xor(s, 8, 64);
    if (g == 0) sq[row] = s;

    if (blockIdx.x == 0) {
        for (int i = tid; i < B; i += 256) outbits[i] = 0x7f800000u;
    }
}

// Stage one 128-fact fp4 tile (24 KB, all of K) into buf. LDS layout
// [kk][row128][ch16B]: iid*16 = kk*8192 + row*64 + ch*16.  (R16-verified)
__device__ __forceinline__ void stage_tile128(const unsigned char* __restrict__ Ff,
                                              unsigned char* buf, int n0, int tid) {
#pragma unroll
    for (int it = 0; it < 6; ++it) {
        int iid = it * 256 + tid;  // [0,1536)
        gl2lds16(Ff + (size_t)(n0 + ((iid >> 2) & 127)) * 192 +
                     (iid >> 9) * 64 + (iid & 3) * 16,
                 buf + (size_t)iid * 16);
    }
}

// ---------- R18 FULL GEMM (best measured): 128-tiles, 2 blocks/CU ----------
__global__ __launch_bounds__(256, 2)
void gemm_pipe_kernel(const unsigned char* __restrict__ Qf,  // [M][192] fp4 permuted
                      const unsigned char* __restrict__ Ff,  // [N][192] fp4 permuted
                      const float* __restrict__ qsq, const float* __restrict__ fsq,
                      unsigned int* __restrict__ outbits, int ntiles) {
    __shared__ __align__(16) unsigned char Bs[2][24576];  // 2 x 24 KB

    const int tid = threadIdx.x;
    const int lane = tid & 63;
    const int wid = tid >> 6;          // wave owns m-rows [wid*64, wid*64+64)
    const int col = lane & 15, quad = lane >> 4;
    const int swc = ((col >> 1) & 3);
    const int cp = (quad ^ swc) * 16;  // swizzled chunk byte offset
    const int m0 = blockIdx.y * 256;
    const int nbase = blockIdx.x * (ntiles * 128);
    const int SCL = 0x7f;  // e8m0 exponent 127 -> scale = 2^0 = 1.0

    // A operand fully resident AND pre-widened: 4 i x 3 kk x 8 regs = 96 VGPRs
    // (high halves zero, written once -> no widen movs inside the loop).
    i32x8 af8[4][3];
#pragma unroll
    for (int i = 0; i < 4; ++i) {
        const unsigned char* base = Qf + (size_t)(m0 + wid * 64 + i * 16 + col) * 192;
#pragma unroll
        for (int kk = 0; kk < 3; ++kk) {
            i32x4 t = *(const i32x4*)(base + kk * 64 + cp);
            af8[i][kk][0] = t[0]; af8[i][kk][1] = t[1];
            af8[i][kk][2] = t[2]; af8[i][kk][3] = t[3];
            af8[i][kk][4] = 0; af8[i][kk][5] = 0;
            af8[i][kk][6] = 0; af8[i][kk][7] = 0;
        }
    }

    // persistent zero C operand (each half's kk==0 MFMA writes acc = A*B + 0)
    const f32x4 zero4 = {0.f, 0.f, 0.f, 0.f};

    float rowmin[16];
#pragma unroll
    for (int v = 0; v < 16; ++v) rowmin[v] = 3.0e38f;

    // fsq seeds for the 8 column groups of the current/next tile
    float fs_cur[8], fs_nxt[8];
#pragma unroll
    for (int j = 0; j < 8; ++j) fs_cur[j] = fsq[nbase + j * 16 + col];

    // Three rotating B tuples; high halves zeroed ONCE (persist across tiles).
    i32x8 bv[3];
#pragma unroll
    for (int r = 0; r < 3; ++r) {
        bv[r][4] = 0; bv[r][5] = 0; bv[r][6] = 0; bv[r][7] = 0;
    }

    f32x4 acc[4][4];  // restarted each half via zero-C at kk==0

    // Step s in [0,24): half h = s/12, u = s%12, kk = u>>2, j = u&3.
    // kk-outer/j-inner: consecutive steps hit different acc[j] (dep dist 4).
#define LOADB(S, R)                                                            \
        {                                                                      \
            const int _h = (S) / 12, _u = (S) % 12;                            \
            const int _kk = _u >> 2, _j = _u & 3;                              \
            i32x4 _t = *(const i32x4*)(bb + _kk * 8192 +                       \
                                       (_h * 64 + _j * 16 + col) * 64 + cp);   \
            bv[R][0] = _t[0]; bv[R][1] = _t[1];                                \
            bv[R][2] = _t[2]; bv[R][3] = _t[3];                                \
        }
#define MFMAS(S, R)                                                            \
        {                                                                      \
            const int _u = (S) % 12;                                           \
            const int _kk = _u >> 2, _j = _u & 3;                              \
            if (_kk == 0) {                                                    \
                _Pragma("unroll") for (int _i = 0; _i < 4; ++_i)               \
                    acc[_i][_j] = __builtin_amdgcn_mfma_scale_f32_16x16x128_f8f6f4( \
                        af8[_i][0], bv[R], zero4, 4, 4, 0, SCL, 0, SCL);       \
            } else {                                                           \
                _Pragma("unroll") for (int _i = 0; _i < 4; ++_i)               \
                    acc[_i][_j] = __builtin_amdgcn_mfma_scale_f32_16x16x128_f8f6f4( \
                        af8[_i][_kk], bv[R], acc[_i][_j], 4, 4, 0, SCL, 0, SCL); \
            }                                                                  \
        }
#define FOLDJ(J, FS)                                                           \
        {                                                                      \
            _Pragma("unroll") for (int _i = 0; _i < 4; ++_i)                   \
                _Pragma("unroll") for (int _r = 0; _r < 4; ++_r)               \
                    rowmin[_i * 4 + _r] = fminf(rowmin[_i * 4 + _r],           \
                        fmaf(-2.0f, acc[_i][(J)][_r], (FS)));                  \
        }

    stage_tile128(Ff, Bs[0], nbase, tid);  // prologue prefetch
    for (int t = 0; t < ntiles; ++t) {
        __syncthreads();  // drains tile t's staging (issued one full round ago)
        if (t + 1 < ntiles) {
            stage_tile128(Ff, Bs[(t + 1) & 1], nbase + (t + 1) * 128, tid);
#pragma unroll
            for (int j = 0; j < 8; ++j)
                fs_nxt[j] = fsq[nbase + (t + 1) * 128 + j * 16 + col];
        }
        const unsigned char* bb = Bs[t & 1];

        // 24 steps, depth-2 B ds_read pipeline. Fold schedule (in MFMA
        // shadow): half h's j=0,1,2 fold at u=9,10,11 (acc[j] final after
        // u=8+j); half-0's j=3 folds at s=12 (acc[3] untouched until u=3 of
        // half 1); half-1's j=3 folds after the loop.
        __builtin_amdgcn_s_setprio(1);
        LOADB(0, 0);
        LOADB(1, 1);
#pragma unroll
        for (int s = 0; s < 24; ++s) {
            if (s + 2 < 24) LOADB(s + 2, (s + 2) % 3);
            {
                const int u = s % 12, h = s / 12;
                if (u >= 9) FOLDJ(u - 9, fs_cur[h * 4 + (u - 9)]);
                if (s == 12) FOLDJ(3, fs_cur[3]);
            }
            MFMAS(s, s % 3);
        }
        __builtin_amdgcn_s_setprio(0);
        FOLDJ(3, fs_cur[7]);

#pragma unroll
        for (int j = 0; j < 8; ++j) fs_cur[j] = fs_nxt[j];
    }
#undef LOADB
#undef MFMAS
#undef FOLDJ

    // per-wave epilogue (R15-verified; each wave owns exclusive m-rows):
    // min over 16 cols, then ONE atomic per row. No counters, no fences.
#pragma unroll
    for (int v = 0; v < 16; ++v) {
        float mn = rowmin[v];
#pragma unroll
        for (int off = 1; off < 16; off <<= 1) mn = fminf(mn, __shfl_xor(mn, off, 64));
        rowmin[v] = mn;
    }
    if (col == 0) {
#pragma unroll
        for (int i = 0; i < 4; ++i)
#pragma unroll
            for (int r = 0; r < 4; ++r) {
                const int row = m0 + wid * 64 + i * 16 + quad * 4 + r;
                float d2 = fmaxf(qsq[row] + rowmin[i * 4 + r], 0.0f);
                atomicMin(outbits + row, __float_as_uint(d2));
            }
    }
}

__global__ void finalize_kernel(float* out, int n) {
    int i = blockIdx.x * blockDim.x + threadIdx.x;
    if (i < n) {
        float d2 = __uint_as_float(((unsigned int*)out)[i]);
        out[i] = expf(-0.5f * d2);
    }
}

// ---------- fallbacks (verified in earlier rounds) ----------
__global__ void init_min_kernel(unsigned int* ob, int n) {
    int i = blockIdx.x * blockDim.x + threadIdx.x;
    if (i < n) ob[i] = 0x7f800000u;
}

__global__ void conv_rows_kernel(const float* __restrict__ p0, const float* __restrict__ p1,
                                 const float* __restrict__ p2, unsigned short* __restrict__ outb,
                                 float* __restrict__ sq, int nrows) {
    const int lane = threadIdx.x & 63;
    const int wave = threadIdx.x >> 6;
    const int row = blockIdx.x * 4 + wave;
    if (row >= nrows) return;
    float s = 0.f;
#pragma unroll
    for (int c = 0; c < 6; ++c) {
        int k = c * 64 + lane;
        const float* src = (k < 128) ? p0 : (k < 256) ? p1 : p2;
        float v = src[(size_t)row * 128 + (k & 127)];
        s += v * v;
        if (outb) outb[(size_t)row * 384 + k] = f2bf(v);
    }
#pragma unroll
    for (int off = 32; off >= 1; off >>= 1) s += __shfl_xor(s, off, 64);
    if (lane == 0) sq[row] = s;
}

__global__ __launch_bounds__(256)
void gemm_lean_kernel(const unsigned short* __restrict__ Qb,
                      const float* __restrict__ f0, const float* __restrict__ f1,
                      const float* __restrict__ f2,
                      const float* __restrict__ qsq, const float* __restrict__ fsq,
                      unsigned int* __restrict__ outbits, int K) {
    __shared__ __align__(16) unsigned short As[128 * 32];
    __shared__ __align__(16) unsigned short Bs[128 * 32];
    __shared__ float smin[128 * 2];

    const int tid = threadIdx.x;
    const int lane = tid & 63;
    const int wid = tid >> 6;
    const int wm = wid >> 1, wn = wid & 1;
    const int col = lane & 15, quad = lane >> 4;
    const int m0 = blockIdx.x * 128;
    const int n0 = blockIdx.y * 128;

    f32x4 acc[4][4];
#pragma unroll
    for (int i = 0; i < 4; ++i)
#pragma unroll
        for (int j = 0; j < 4; ++j) {
            f32x4 z = {0.f, 0.f, 0.f, 0.f};
            acc[i][j] = z;
        }

    const int nk = K >> 5;
    for (int kk = 0; kk < nk; ++kk) {
        const int k0 = kk << 5;
        __syncthreads();
#pragma unroll
        for (int it = 0; it < 2; ++it) {
            int iid = it * 256 + tid;
            int row = iid >> 2, ch = iid & 3;
            gl2lds16(Qb + ((size_t)(m0 + row) * K + k0 + ch * 8), As + (row * 32 + ch * 8));
        }
        const float* src = (k0 < 128) ? f0 : (k0 < 256) ? f1 : f2;
        const int kp = k0 & 127;
#pragma unroll
        for (int it = 0; it < 4; ++it) {
            int iid = it * 256 + tid;
            int row = iid >> 3, ch = iid & 7;
            const float4 v = *(const float4*)(src + (size_t)(n0 + row) * 128 + kp + ch * 4);
            us4 w = {f2bf(v.x), f2bf(v.y), f2bf(v.z), f2bf(v.w)};
            *(us4*)(Bs + (row * 32 + ch * 4)) = w;
        }
        __syncthreads();

        bf16x8 afr[4], bfv[4];
#pragma unroll
        for (int i = 0; i < 4; ++i)
            afr[i] = *(const bf16x8*)(As + ((wm * 64 + i * 16 + col) * 32 + quad * 8));
#pragma unroll
        for (int j = 0; j < 4; ++j)
            bfv[j] = *(const bf16x8*)(Bs + ((wn * 64 + j * 16 + col) * 32 + quad * 8));
#pragma unroll
        for (int i = 0; i < 4; ++i)
#pragma unroll
            for (int j = 0; j < 4; ++j)
                acc[i][j] = __builtin_amdgcn_mfma_f32_16x16x32_bf16(afr[i], bfv[j], acc[i][j], 0, 0, 0);
    }

    float fs[4];
#pragma unroll
    for (int j = 0; j < 4; ++j) fs[j] = fsq[n0 + wn * 64 + j * 16 + col];
#pragma unroll
    for (int i = 0; i < 4; ++i) {
#pragma unroll
        for (int r = 0; r < 4; ++r) {
            const int mrow = wm * 64 + i * 16 + quad * 4 + r;
            const float qs = qsq[m0 + mrow];
            float mn = 3.0e38f;
#pragma unroll
            for (int j = 0; j < 4; ++j) {
                float d2 = qs + fs[j] - 2.0f * acc[i][j][r];
                mn = fminf(mn, fmaxf(d2, 0.0f));
            }
#pragma unroll
            for (int off = 1; off < 16; off <<= 1) mn = fminf(mn, __shfl_xor(mn, off, 64));
            if (col == 0) smin[mrow * 2 + wn] = mn;
        }
    }
    __syncthreads();
    if (tid < 128) {
        float v = fminf(smin[tid * 2 + 0], smin[tid * 2 + 1]);
        atomicMin(outbits + m0 + tid, __float_as_uint(v));
    }
}

__global__ __launch_bounds__(256)
void tier3_kernel(const float* __restrict__ rel, const float* __restrict__ a1,
                  const float* __restrict__ a2, const float* __restrict__ fr,
                  const float* __restrict__ fa1, const float* __restrict__ fa2,
                  unsigned int* __restrict__ outbits) {
    __shared__ float qs[16][384];
    __shared__ float red[4][16];
    const int tid = threadIdx.x;
    const int qbase = blockIdx.y * 16;
    const int fbase = blockIdx.x * 2048;
    for (int i = tid; i < 16 * 384; i += 256) {
        int r = i / 384, c = i % 384;
        const float* src = (c < 128) ? rel : (c < 256) ? a1 : a2;
        qs[r][c] = src[(size_t)(qbase + r) * 128 + (c & 127)];
    }
    __syncthreads();
    float mn[16];
#pragma unroll
    for (int q = 0; q < 16; ++q) mn[q] = 3.0e38f;
    for (int fi = 0; fi < 2048; fi += 256) {
        const int f = fbase + fi + tid;
        float acc[16];
#pragma unroll
        for (int q = 0; q < 16; ++q) acc[q] = 0.f;
#pragma unroll
        for (int p = 0; p < 3; ++p) {
            const float* fptr = ((p == 0) ? fr : (p == 1) ? fa1 : fa2) + (size_t)f * 128;
            for (int k4 = 0; k4 < 32; ++k4) {
                const float4 fv = *(const float4*)(fptr + k4 * 4);
#pragma unroll
                for (int q = 0; q < 16; ++q) {
                    float d0 = fv.x - qs[q][p * 128 + k4 * 4 + 0];
                    float d1 = fv.y - qs[q][p * 128 + k4 * 4 + 1];
                    float d2 = fv.z - qs[q][p * 128 + k4 * 4 + 2];
                    float d3 = fv.w - qs[q][p * 128 + k4 * 4 + 3];
                    acc[q] += d0 * d0 + d1 * d1 + d2 * d2 + d3 * d3;
                }
            }
        }
#pragma unroll
        for (int q = 0; q < 16; ++q) mn[q] = fminf(mn[q], fmaxf(acc[q], 0.f));
    }
#pragma unroll
    for (int q = 0; q < 16; ++q) {
        float v = mn[q];
#pragma unroll
        for (int off = 32; off >= 1; off >>= 1) v = fminf(v, __shfl_xor(v, off, 64));
        if ((tid & 63) == 0) red[tid >> 6][q] = v;
    }
    __syncthreads();
    if (tid < 16) {
        float v = fminf(fminf(red[0][tid], red[1][tid]), fminf(red[2][tid], red[3][tid]));
        atomicMin(outbits + qbase + tid, __float_as_uint(v));
    }
}

extern "C" void kernel_launch(void* const* d_in, const int* in_sizes, int n_in,
                              void* d_out, int out_size, void* d_ws, size_t ws_size,
                              hipStream_t stream) {
    const float* rel = (const float*)d_in[0];
    const float* a1 = (const float*)d_in[1];
    const float* a2 = (const float*)d_in[2];
    const float* fr = (const float*)d_in[3];
    const float* fa1 = (const float*)d_in[4];
    const float* fa2 = (const float*)d_in[5];

    const int E = 128, K = 384;
    const int B = in_sizes[0] / E;   // 2048
    const int F = in_sizes[3] / E;   // 65536

    float* out = (float*)d_out;
    unsigned int* outbits = (unsigned int*)d_out;

    const size_t ff_bytes = (size_t)F * 192;     // 12 MB facts fp4
    const size_t qf_bytes = (size_t)B * 192;     // 384 KB queries fp4
    const size_t need_full = ff_bytes + qf_bytes + (size_t)F * 4 + (size_t)B * 4;
    const size_t qb_bytes = (size_t)B * K * 2;
    const size_t need_lean = qb_bytes + (size_t)F * 4 + (size_t)B * 4;

    const bool shapes_ok = (B % 256 == 0) && (F % 1024 == 0);
    if (ws_size >= need_full && shapes_ok) {
        unsigned char* Ff = (unsigned char*)d_ws;
        unsigned char* Qf = (unsigned char*)d_ws + ff_bytes;
        float* fsq = (float*)((char*)d_ws + ff_bytes + qf_bytes);
        float* qsq = fsq + F;
        prep_kernel<<<B / 16 + F / 16, 256, 0, stream>>>(rel, a1, a2, fr, fa1, fa2,
                                                         Qf, Ff, qsq, fsq, outbits, B, F);
        // grid: x = n-groups of 1024 facts (8 tiles of 128, double-buffered),
        // y = m-tiles of 256. 512 blocks = exactly 2 blocks/CU, one generation.
        gemm_pipe_kernel<<<dim3(F / 1024, B / 256), 256, 0, stream>>>(
            Qf, Ff, qsq, fsq, outbits, 8);
    } else if (ws_size >= need_lean && B % 128 == 0 && F % 128 == 0) {
        unsigned short* Qb = (unsigned short*)d_ws;
        float* fsq = (float*)((char*)d_ws + qb_bytes);
        float* qsq = fsq + F;
        init_min_kernel<<<(B + 255) / 256, 256, 0, stream>>>(outbits, B);
        conv_rows_kernel<<<B / 4, 256, 0, stream>>>(rel, a1, a2, Qb, qsq, B);
        conv_rows_kernel<<<F / 4, 256, 0, stream>>>(fr, fa1, fa2, nullptr, fsq, F);
        gemm_lean_kernel<<<dim3(B / 128, F / 128), 256, 0, stream>>>(
            Qb, fr, fa1, fa2, qsq, fsq, outbits, K);
    } else {
        init_min_kernel<<<(B + 255) / 256, 256, 0, stream>>>(outbits, B);
        tier3_kernel<<<dim3(F / 2048, B / 16), 256, 0, stream>>>(rel, a1, a2, fr, fa1, fa2, outbits);
    }

    finalize_kernel<<<(B + 255) / 256, 256, 0, stream>>>(out, B);
}